// Round 7
// baseline (173.807 us; speedup 1.0000x reference)
//
#include <hip/hip_runtime.h>
#include <hip/hip_bf16.h>

// Problem constants
#define DIM_X 256
#define DIM_E 256
#define DD    512          // DIM_X + DIM_E
#define NB    8            // batch
#define NN    2048         // sequence
#define SCALE 0.044194173824159216f   // (DIM_X+DIM_E)^-0.5
#define GRID  512          // 2 blocks/CU x 256 CU, fully resident

typedef __attribute__((ext_vector_type(8))) __bf16 bf16x8;
typedef __attribute__((ext_vector_type(4))) float  f32x4;
using bf16 = __hip_bfloat16;

__device__ __forceinline__ unsigned short f2bf(float f) {
  union { __hip_bfloat16 h; unsigned short u; } c;
  c.h = __float2bfloat16(f);
  return c.u;
}

// async global->LDS 16B copy. LDS dest must be wave-uniform base + lane*16.
__device__ __forceinline__ void async_lds16(const void* g, void* l) {
  using u32_as3 = __attribute__((address_space(3))) unsigned int;
  using u32_as1 = const __attribute__((address_space(1))) unsigned int;
  __builtin_amdgcn_global_load_lds(
      reinterpret_cast<u32_as1*>(reinterpret_cast<unsigned long long>(g)),
      reinterpret_cast<u32_as3*>(static_cast<unsigned int>(
          reinterpret_cast<unsigned long long>(l))),
      16, 0, 0);
}

// ---------------------------------------------------------------------------
// Grid barrier v4: DISTRIBUTED SENSE BROADCAST.
// R1/R4/R6 all cost ~26us/barrier regardless of arrival tree or poll style.
// Invariant across them: ~500 blocks polled ONE line. Agent-scope loads
// bypass the non-coherent L2 -> every poll is a fabric transaction to the
// same address; at ~1000 polls/us vs ~500/us same-line service rate the
// queue saturates, and the releaser's flip + late arrivals queue BEHIND the
// storm. Fix: releaser broadcasts the flipped sense to 16 separate 128B
// lines; each block polls only its bucket's line (32 pollers/line at
// s_sleep(2) ~ 150 loads/us/line -- ~100x under saturation).
// Ordering chain: arrival fetch_add(acq_rel) on bucket counter -> bucket-
// last fetch_add(acq_rel) on g_gcnt -> releaser's release stores to the 16
// sense lines -> waiter's relaxed load + acquire fence. Self-restoring
// across graph replays: counters return to 0, all sense lines flip together
// (entry-read of own line is race-free: barrier k cannot complete before
// every block has entered). Fallback fetch_add(0) every-4096 is a benign
// RMW (writes back the read value) kept as staleness insurance.
// ---------------------------------------------------------------------------
#define NBUCKETS 16
#define BUCKET_SZ (GRID / NBUCKETS)  // 32
__device__ __align__(128) unsigned g_bcnt[NBUCKETS * 32] = {};
__device__ __align__(128) unsigned g_gcnt = 0u;
__device__ __align__(128) unsigned g_sense_bc[NBUCKETS * 32] = {};

__device__ __forceinline__ void grid_sync(int bx) {
  __syncthreads();  // each wave drains its own vmcnt/lgkm before s_barrier
  if (threadIdx.x == 0) {
    const int bkt = bx & (NBUCKETS - 1);
    unsigned* myline = &g_sense_bc[bkt * 32];
    unsigned s = __hip_atomic_load(myline, __ATOMIC_RELAXED,
                                   __HIP_MEMORY_SCOPE_AGENT);
    unsigned prev = __hip_atomic_fetch_add(&g_bcnt[bkt * 32], 1u,
                                           __ATOMIC_ACQ_REL,
                                           __HIP_MEMORY_SCOPE_AGENT);
    if (prev == BUCKET_SZ - 1) {           // last of bucket
      __hip_atomic_store(&g_bcnt[bkt * 32], 0u, __ATOMIC_RELAXED,
                         __HIP_MEMORY_SCOPE_AGENT);
      unsigned gp = __hip_atomic_fetch_add(&g_gcnt, 1u, __ATOMIC_ACQ_REL,
                                           __HIP_MEMORY_SCOPE_AGENT);
      if (gp == NBUCKETS - 1) {            // releaser: broadcast the flip
        __hip_atomic_store(&g_gcnt, 0u, __ATOMIC_RELAXED,
                           __HIP_MEMORY_SCOPE_AGENT);
#pragma unroll
        for (int i = 0; i < NBUCKETS; i++)
          __hip_atomic_store(&g_sense_bc[i * 32], s ^ 1u, __ATOMIC_RELEASE,
                             __HIP_MEMORY_SCOPE_AGENT);
      }
    }
    unsigned n = 0;
    for (;;) {
      unsigned v = __hip_atomic_load(myline, __ATOMIC_RELAXED,
                                     __HIP_MEMORY_SCOPE_AGENT);
      if (v != s) break;
      if ((++n & 4095u) == 0u)             // rare staleness fallback (benign)
        (void)__hip_atomic_fetch_add(myline, 0u, __ATOMIC_RELAXED,
                                     __HIP_MEMORY_SCOPE_AGENT);
      __builtin_amdgcn_s_sleep(2);
    }
    __builtin_amdgcn_fence(__ATOMIC_ACQUIRE, "agent");
  }
  __syncthreads();
}

// ---------------------------------------------------------------------------
// One BMxBN tile of C = alpha * Acat @ Bcat^T (operands K-major bf16).
// Proven dbuf version (rounds 2-6): 4 waves 2x2, 16x16x32 MFMA, XOR-swizzled
// LDS, global_load_lds width-16 staging, stage(t+1) before compute(t), one
// barrier per K-step. smem = 2*(BM+BN)*BKt*2 bytes.
// ---------------------------------------------------------------------------
template <int BM, int BN, int BKt, bool OUT_BF16, int ASPLIT, int BSPLIT>
__device__ void gemm_tile(const bf16* __restrict__ A0,
                          const bf16* __restrict__ A1,
                          const bf16* __restrict__ B0,
                          const bf16* __restrict__ B1, void* __restrict__ Cv,
                          int K, int lda, int ldb, int ldc, float alpha,
                          char* smem) {
  constexpr int CPT  = BKt / 8;
  constexpr int KS   = BKt / 32;
  constexpr int WTM  = BM / 2, WTN = BN / 2;
  constexpr int IM   = WTM / 16, IN = WTN / 16;
  constexpr int CA   = BM * CPT, CB = BN * CPT;
  constexpr int BUFB = (BM + BN) * BKt * 2;

  const int tid  = threadIdx.x;
  const int lane = tid & 63;
  const int wave = tid >> 6;
  const int lm   = lane & 15;
  const int quad = lane >> 4;
  const int wm   = (wave >> 1) * WTM;
  const int wn   = (wave & 1) * WTN;

  auto stage = [&](int t, int buf) {
    const int k0 = t * BKt;
    const bf16* Ak = A0; int ka = k0;
    if (ASPLIT > 0 && k0 >= ASPLIT) { Ak = A1; ka = k0 - ASPLIT; }
    const bf16* Bk = B0; int kb = k0;
    if (BSPLIT > 0 && k0 >= BSPLIT) { Bk = B1; kb = k0 - BSPLIT; }
    bf16* sA = (bf16*)(smem + (size_t)buf * BUFB);
    bf16* sB = sA + BM * BKt;
#pragma unroll
    for (int c = tid; c < CA; c += 256) {
      int row = c / CPT;
      int cb  = (c % CPT) ^ (row % CPT);
      async_lds16(Ak + (long)row * lda + ka + cb * 8, sA + (size_t)c * 8);
    }
#pragma unroll
    for (int c = tid; c < CB; c += 256) {
      int row = c / CPT;
      int cb  = (c % CPT) ^ (row % CPT);
      async_lds16(Bk + (long)row * ldb + kb + cb * 8, sB + (size_t)c * 8);
    }
  };

  f32x4 acc[IM][IN];
#pragma unroll
  for (int i = 0; i < IM; i++)
#pragma unroll
    for (int j = 0; j < IN; j++) acc[i][j] = (f32x4){0.f, 0.f, 0.f, 0.f};

  const int nt = K / BKt;
  stage(0, 0);
  __syncthreads();
  int cur = 0;
  for (int t = 0; t < nt; ++t) {
    if (t + 1 < nt) stage(t + 1, cur ^ 1);
    const bf16* sA = (const bf16*)(smem + (size_t)cur * BUFB);
    const bf16* sB = sA + BM * BKt;
    bf16x8 af[KS][IM], bfr[KS][IN];
#pragma unroll
    for (int s = 0; s < KS; s++) {
#pragma unroll
      for (int i = 0; i < IM; i++) {
        int r = wm + i * 16 + lm;
        af[s][i] = *(const bf16x8*)&sA[r * BKt +
                                       (((s * 4 + quad) ^ (r % CPT)) * 8)];
      }
#pragma unroll
      for (int j = 0; j < IN; j++) {
        int r = wn + j * 16 + lm;
        bfr[s][j] = *(const bf16x8*)&sB[r * BKt +
                                        (((s * 4 + quad) ^ (r % CPT)) * 8)];
      }
    }
#pragma unroll
    for (int s = 0; s < KS; s++)
#pragma unroll
      for (int i = 0; i < IM; i++)
#pragma unroll
        for (int j = 0; j < IN; j++)
          acc[i][j] = __builtin_amdgcn_mfma_f32_16x16x32_bf16(
              af[s][i], bfr[s][j], acc[i][j], 0, 0, 0);
    __syncthreads();
    cur ^= 1;
  }

  // C/D layout (16x16): col = lane&15, row = (lane>>4)*4 + reg  [m89-verified]
  const int baseRow = wm + quad * 4;
  const int baseCol = wn + lm;
  if (OUT_BF16) {
    bf16* Cb = (bf16*)Cv;
#pragma unroll
    for (int i = 0; i < IM; i++)
#pragma unroll
      for (int r = 0; r < 4; r++) {
        int row = baseRow + i * 16 + r;
#pragma unroll
        for (int j = 0; j < IN; j++)
          Cb[(long)row * ldc + baseCol + j * 16] =
              __float2bfloat16(acc[i][j][r] * alpha);
      }
  } else {
    float* Cf = (float*)Cv;
#pragma unroll
    for (int i = 0; i < IM; i++)
#pragma unroll
      for (int r = 0; r < 4; r++) {
        int row = baseRow + i * 16 + r;
#pragma unroll
        for (int j = 0; j < IN; j++)
          Cf[(long)row * ldc + baseCol + j * 16] = acc[i][j][r] * alpha;
      }
  }
}

// pack job descriptor (R0-proven block-cooperative 32x32 tile pack)
struct PackJob {
  const float* src; int ld;
  bf16* dS; int ldS;
  bf16* dT; int ldT;
};

// ---------------------------------------------------------------------------
// Fused pipeline v4 == v3 (R6, passed) with ONLY the barrier replaced.
//   phase0: pack, 5120 jobs grid-strided (10/block), block-cooperative LDS
//           tile, next-job global load issued before the current job's two
//           syncs. x-jobs XCD-affine (j&7 == bx&7).
//   phase1: blocks 0-255: M half-K partials, 128x64 tiles, K=1024;
//           blocks 256-319: W2T = WqT@WkT^T; rest idle at the barrier.
//   phase2: 512 blocks, R = SCALE*(M1+M2)@W2T^T K-concat (verified R1-R6).
//   phase3: 512 blocks, out = [xb|eb] @ R^T, 64x128 tiles (verified).
// All phases <=48KB LDS; launch_bounds(256,2) -> all 512 blocks resident.
// ---------------------------------------------------------------------------
__global__ __launch_bounds__(256, 2) void fused4_k(
    const float* __restrict__ x, const float* __restrict__ e,
    const float* __restrict__ Wq, const float* __restrict__ Wk,
    bf16* __restrict__ xb, bf16* __restrict__ VT, bf16* __restrict__ eb,
    bf16* __restrict__ ET, bf16* __restrict__ WqT, bf16* __restrict__ WkT,
    bf16* __restrict__ W2T, bf16* __restrict__ M1, bf16* __restrict__ M2,
    bf16* __restrict__ R, float* __restrict__ out) {
  __shared__ __align__(16) char smem[49152];
  const int bx  = blockIdx.x;
  const int tid = threadIdx.x;

  // ---- phase 0: pack -----------------------------------------------------
  {
    float (*tile)[33] = reinterpret_cast<float (*)[33]>(smem);
    const int lrow = tid >> 3;        // 0..31
    const int lc4  = (tid & 7) * 4;   // float4 col
    auto desc = [&](int j) -> PackJob {
      PackJob P;
      if (j < 4096) {
        int b = j & 7;                // XCD-affine
        int slot = j >> 3;
        int r = slot >> 3, c = slot & 7;
        P.src = x + ((long)b * NN + r * 32) * DIM_X + c * 32; P.ld = DIM_X;
        P.dS = xb + ((long)b * NN + r * 32) * DIM_X + c * 32; P.ldS = DIM_X;
        P.dT = VT + ((long)b * DIM_X + c * 32) * NN + r * 32; P.ldT = NN;
      } else if (j < 4608) {
        int i = j - 4096, r = i >> 3, c = i & 7;
        P.src = e + ((long)r * 32) * DIM_E + c * 32; P.ld = DIM_E;
        P.dS = eb + ((long)r * 32) * DIM_E + c * 32; P.ldS = DIM_E;
        P.dT = ET + ((long)c * 32) * NN + r * 32; P.ldT = NN;
      } else if (j < 4864) {
        int i = j - 4608, r = i >> 4, c = i & 15;
        P.src = Wq + ((long)r * 32) * DD + c * 32; P.ld = DD;
        P.dS = nullptr; P.ldS = 0;
        P.dT = WqT + ((long)c * 32) * DD + r * 32; P.ldT = DD;
      } else {
        int i = j - 4864, r = i >> 4, c = i & 15;
        P.src = Wk + ((long)r * 32) * DD + c * 32; P.ld = DD;
        P.dS = nullptr; P.ldS = 0;
        P.dT = WkT + ((long)c * 32) * DD + r * 32; P.ldT = DD;
      }
      return P;
    };
    PackJob P = desc(bx);
    float4 v = *(const float4*)(P.src + (long)lrow * P.ld + lc4);
    for (int j = bx; j < 5120; j += GRID) {
      PackJob Pn; float4 vn;
      const bool more = (j + GRID) < 5120;
      if (more) {                      // issue next-job load NOW (overlaps
        Pn = desc(j + GRID);           //  both __syncthreads below)
        vn = *(const float4*)(Pn.src + (long)lrow * Pn.ld + lc4);
      }
      if (P.dS) {
        ushort4 o;
        o.x = f2bf(v.x); o.y = f2bf(v.y); o.z = f2bf(v.z); o.w = f2bf(v.w);
        *(ushort4*)((unsigned short*)P.dS + (long)lrow * P.ldS + lc4) = o;
      }
      tile[lrow][lc4 + 0] = v.x; tile[lrow][lc4 + 1] = v.y;
      tile[lrow][lc4 + 2] = v.z; tile[lrow][lc4 + 3] = v.w;
      __syncthreads();
      {
        ushort4 o;
        o.x = f2bf(tile[lc4 + 0][lrow]);
        o.y = f2bf(tile[lc4 + 1][lrow]);
        o.z = f2bf(tile[lc4 + 2][lrow]);
        o.w = f2bf(tile[lc4 + 3][lrow]);
        *(ushort4*)((unsigned short*)P.dT + (long)lrow * P.ldT + lc4) = o;
      }
      __syncthreads();
      if (more) { P = Pn; v = vn; }
    }
  }
  grid_sync(bx);

  // ---- phase 1: M split-K partials + W2T --------------------------------
  if (bx < 256) {
    const int b   = bx & 7;
    const int idx = bx >> 3;              // 0..31
    const int kh  = idx & 1;              // K half
    const int mt  = (idx >> 1) & 1;       // row tile (2 x 128 = 256)
    const int nt  = idx >> 2;             // col tile (8 x 64 = 512)
    const bf16* A = VT + (long)b * DIM_X * NN + (long)mt * 128 * NN +
                    kh * 1024;
    const bf16* B = (nt < 4)
        ? VT + (long)b * DIM_X * NN + (long)nt * 64 * NN + kh * 1024
        : ET + (long)(nt - 4) * 64 * NN + kh * 1024;
    bf16* C = (kh ? M2 : M1) + (long)b * DIM_X * DD + (long)mt * 128 * DD +
              nt * 64;
    gemm_tile<128, 64, 64, true, 0, 0>(A, nullptr, B, nullptr, C, 1024, NN,
                                       NN, DD, 1.0f, smem);
  } else if (bx < 320) {
    const int i = bx - 256;
    int r2 = i >> 3, c2 = i & 7;
    gemm_tile<64, 64, 64, true, 0, 0>(
        WqT + (long)r2 * 64 * DD, nullptr, WkT + (long)c2 * 64 * DD, nullptr,
        W2T + (long)r2 * 64 * DD + c2 * 64, DD, DD, DD, DD, 1.0f, smem);
  }
  grid_sync(bx);

  // ---- phase 2: R = SCALE * (M1+M2) @ W2T^T (K-concat, verified) --------
  {
    const int b = bx & 7, r = (bx >> 3) & 7, c = bx >> 6;
    const bf16* a0 = M1 + (long)b * DIM_X * DD + (long)r * 32 * DD;
    const bf16* a1 = M2 + (long)b * DIM_X * DD + (long)r * 32 * DD;
    const bf16* w  = W2T + (long)c * 64 * DD;
    gemm_tile<32, 64, 128, true, 512, 512>(
        a0, a1, w, w,
        R + (long)b * DIM_X * DD + (long)r * 32 * DD + c * 64, 1024, DD, DD,
        DD, SCALE, smem);
  }
  grid_sync(bx);

  // ---- phase 3: out = [xb|eb] @ R^T (64x128, fp32 out, verified) --------
  {
    const int b = bx & 7, m = (bx >> 3) & 31, n = (bx >> 8) & 1;
    gemm_tile<64, 128, 64, false, 256, 0>(
        xb + (long)b * NN * DIM_X + (long)m * 64 * DIM_X,
        eb + (long)m * 64 * DIM_E,
        R + (long)b * DIM_X * DD + (long)n * 128 * DD, nullptr,
        out + (long)b * NN * DIM_X + (long)m * 64 * DIM_X + n * 128, DD,
        DIM_X, DD, DIM_X, 1.0f, smem);
  }
}

// ---------------------------------------------------------------------------

extern "C" void kernel_launch(void* const* d_in, const int* in_sizes, int n_in,
                              void* d_out, int out_size, void* d_ws,
                              size_t ws_size, hipStream_t stream) {
  const float* x  = (const float*)d_in[0];  // (8, 2048, 256)
  const float* e  = (const float*)d_in[1];  // (2048, 256)
  const float* Wq = (const float*)d_in[2];  // (512, 512)
  const float* Wk = (const float*)d_in[3];  // (512, 512)
  float* out = (float*)d_out;               // (8, 2048, 256)

  char* ws = (char*)d_ws;
  size_t off = 0;
  auto alloc = [&](size_t bytes) {
    void* p = ws + off;
    off += (bytes + 255) & ~(size_t)255;
    return p;
  };

  bf16* xb  = (bf16*)alloc((size_t)NB * NN * DIM_X * 2);  // 8.4 MB
  bf16* VT  = (bf16*)alloc((size_t)NB * DIM_X * NN * 2);  // 8.4 MB
  bf16* eb  = (bf16*)alloc((size_t)NN * DIM_E * 2);       // 1 MB
  bf16* ET  = (bf16*)alloc((size_t)DIM_E * NN * 2);       // 1 MB
  bf16* WqT = (bf16*)alloc((size_t)DD * DD * 2);          // 0.5 MB
  bf16* WkT = (bf16*)alloc((size_t)DD * DD * 2);          // 0.5 MB
  bf16* W2T = (bf16*)alloc((size_t)DD * DD * 2);          // 0.5 MB
  bf16* M1  = (bf16*)alloc((size_t)NB * DIM_X * DD * 2);  // 2 MB
  bf16* M2  = (bf16*)alloc((size_t)NB * DIM_X * DD * 2);  // 2 MB
  bf16* R   = (bf16*)alloc((size_t)NB * DIM_X * DD * 2);  // 2 MB

  fused4_k<<<GRID, 256, 0, stream>>>(x, e, Wq, Wk, xb, VT, eb, ET, WqT, WkT,
                                     W2T, M1, M2, R, out);
}

// Round 8
// 131.319 us; speedup vs baseline: 1.3236x; 1.3236x over previous
//
#include <hip/hip_runtime.h>
#include <hip/hip_bf16.h>

// Problem constants
#define DIM_X 256
#define DIM_E 256
#define DD    512          // DIM_X + DIM_E
#define NB    8            // batch
#define NN    2048         // sequence
#define SCALE 0.044194173824159216f   // (DIM_X+DIM_E)^-0.5

typedef __attribute__((ext_vector_type(8))) __bf16 bf16x8;
typedef __attribute__((ext_vector_type(4))) float  f32x4;
using bf16 = __hip_bfloat16;

__device__ __forceinline__ unsigned short f2bf(float f) {
  union { __hip_bfloat16 h; unsigned short u; } c;
  c.h = __float2bfloat16(f);
  return c.u;
}

// async global->LDS 16B copy. LDS dest must be wave-uniform base + lane*16.
__device__ __forceinline__ void async_lds16(const void* g, void* l) {
  using u32_as3 = __attribute__((address_space(3))) unsigned int;
  using u32_as1 = const __attribute__((address_space(1))) unsigned int;
  __builtin_amdgcn_global_load_lds(
      reinterpret_cast<u32_as1*>(reinterpret_cast<unsigned long long>(g)),
      reinterpret_cast<u32_as3*>(static_cast<unsigned int>(
          reinterpret_cast<unsigned long long>(l))),
      16, 0, 0);
}

// ---------------------------------------------------------------------------
// One BMxBN tile of C = alpha * Acat @ Bcat^T (operands K-major bf16).
// Proven dbuf version (rounds 2-7): 4 waves 2x2, 16x16x32 MFMA, XOR-swizzled
// LDS, global_load_lds width-16 staging, stage(t+1) before compute(t), one
// barrier per K-step. smem = 2*(BM+BN)*BKt*2 bytes.
// ASPLIT>0: for k>=ASPLIT read A1 at k-ASPLIT (K-concatenation of A0|A1).
// BSPLIT>0: same for B0|B1 (B1==B0 gives a K-repeated B).
// ---------------------------------------------------------------------------
template <int BM, int BN, int BKt, bool OUT_BF16, int ASPLIT, int BSPLIT>
__device__ void gemm_tile(const bf16* __restrict__ A0,
                          const bf16* __restrict__ A1,
                          const bf16* __restrict__ B0,
                          const bf16* __restrict__ B1, void* __restrict__ Cv,
                          int K, int lda, int ldb, int ldc, float alpha,
                          char* smem) {
  constexpr int CPT  = BKt / 8;
  constexpr int KS   = BKt / 32;
  constexpr int WTM  = BM / 2, WTN = BN / 2;
  constexpr int IM   = WTM / 16, IN = WTN / 16;
  constexpr int CA   = BM * CPT, CB = BN * CPT;
  constexpr int BUFB = (BM + BN) * BKt * 2;

  const int tid  = threadIdx.x;
  const int lane = tid & 63;
  const int wave = tid >> 6;
  const int lm   = lane & 15;
  const int quad = lane >> 4;
  const int wm   = (wave >> 1) * WTM;
  const int wn   = (wave & 1) * WTN;

  auto stage = [&](int t, int buf) {
    const int k0 = t * BKt;
    const bf16* Ak = A0; int ka = k0;
    if (ASPLIT > 0 && k0 >= ASPLIT) { Ak = A1; ka = k0 - ASPLIT; }
    const bf16* Bk = B0; int kb = k0;
    if (BSPLIT > 0 && k0 >= BSPLIT) { Bk = B1; kb = k0 - BSPLIT; }
    bf16* sA = (bf16*)(smem + (size_t)buf * BUFB);
    bf16* sB = sA + BM * BKt;
#pragma unroll
    for (int c = tid; c < CA; c += 256) {
      int row = c / CPT;
      int cb  = (c % CPT) ^ (row % CPT);
      async_lds16(Ak + (long)row * lda + ka + cb * 8, sA + (size_t)c * 8);
    }
#pragma unroll
    for (int c = tid; c < CB; c += 256) {
      int row = c / CPT;
      int cb  = (c % CPT) ^ (row % CPT);
      async_lds16(Bk + (long)row * ldb + kb + cb * 8, sB + (size_t)c * 8);
    }
  };

  f32x4 acc[IM][IN];
#pragma unroll
  for (int i = 0; i < IM; i++)
#pragma unroll
    for (int j = 0; j < IN; j++) acc[i][j] = (f32x4){0.f, 0.f, 0.f, 0.f};

  const int nt = K / BKt;
  stage(0, 0);
  __syncthreads();
  int cur = 0;
  for (int t = 0; t < nt; ++t) {
    if (t + 1 < nt) stage(t + 1, cur ^ 1);
    const bf16* sA = (const bf16*)(smem + (size_t)cur * BUFB);
    const bf16* sB = sA + BM * BKt;
    bf16x8 af[KS][IM], bfr[KS][IN];
#pragma unroll
    for (int s = 0; s < KS; s++) {
#pragma unroll
      for (int i = 0; i < IM; i++) {
        int r = wm + i * 16 + lm;
        af[s][i] = *(const bf16x8*)&sA[r * BKt +
                                       (((s * 4 + quad) ^ (r % CPT)) * 8)];
      }
#pragma unroll
      for (int j = 0; j < IN; j++) {
        int r = wn + j * 16 + lm;
        bfr[s][j] = *(const bf16x8*)&sB[r * BKt +
                                        (((s * 4 + quad) ^ (r % CPT)) * 8)];
      }
    }
#pragma unroll
    for (int s = 0; s < KS; s++)
#pragma unroll
      for (int i = 0; i < IM; i++)
#pragma unroll
        for (int j = 0; j < IN; j++)
          acc[i][j] = __builtin_amdgcn_mfma_f32_16x16x32_bf16(
              af[s][i], bfr[s][j], acc[i][j], 0, 0, 0);
    __syncthreads();
    cur ^= 1;
  }

  // C/D layout (16x16): col = lane&15, row = (lane>>4)*4 + reg  [m89-verified]
  const int baseRow = wm + quad * 4;
  const int baseCol = wn + lm;
  if (OUT_BF16) {
    bf16* Cb = (bf16*)Cv;
#pragma unroll
    for (int i = 0; i < IM; i++)
#pragma unroll
      for (int r = 0; r < 4; r++) {
        int row = baseRow + i * 16 + r;
#pragma unroll
        for (int j = 0; j < IN; j++)
          Cb[(long)row * ldc + baseCol + j * 16] =
              __float2bfloat16(acc[i][j][r] * alpha);
      }
  } else {
    float* Cf = (float*)Cv;
#pragma unroll
    for (int i = 0; i < IM; i++)
#pragma unroll
      for (int r = 0; r < 4; r++) {
        int row = baseRow + i * 16 + r;
#pragma unroll
        for (int j = 0; j < IN; j++)
          Cf[(long)row * ldc + baseCol + j * 16] = acc[i][j][r] * alpha;
      }
  }
}

// ---------------------------------------------------------------------------
// W2R = Wk^T @ Wq (512x512 bf16, row-major [j][i]; W2R[j,i] = W2[i,j] where
// W2 = Wq^T Wk). Computed DIRECTLY from raw fp32 Wq/Wk (no packed WqT/WkT
// needed): per 64-d chunk, cooperative LDS transpose-stage of a 64x64 fp32
// block of Wk (-> A_bf[j][d], K-major bf16) and Wq (-> B_bf[i][d]), then
// 8 MFMAs. One block per 64x64 output tile, K=512 in 8 chunks.
// LDS: scr fp32[64][65] (16640 B) + A_bf/B_bf ushort[64][72] (9216 B each)
// = 35072 B. Bank checks: scr writes/reads 2-way (free), A_bf rows 144 B
// -> b128 reads 2-way (free).
// ---------------------------------------------------------------------------
__device__ void w2r_tile(const float* __restrict__ Wk,
                         const float* __restrict__ Wq,
                         bf16* __restrict__ W2R, int j0, int i0, char* smem) {
  float (*scr)[65] = reinterpret_cast<float (*)[65]>(smem);
  unsigned short* Ab = (unsigned short*)(smem + 16640);  // [64][72]
  unsigned short* Bb = Ab + 64 * 72;
  const int tid  = threadIdx.x;
  const int lane = tid & 63;
  const int wv   = tid >> 6;
  const int lm   = lane & 15;
  const int quad = lane >> 4;
  const int wm   = (wv >> 1) * 32;
  const int wn   = (wv & 1) * 32;
  const int lrow = tid >> 2;         // 0..63 load row (d)
  const int lc   = (tid & 3) * 16;   // 16-float col group
  const int sj   = tid & 63;         // scatter output row (j or i)
  const int sd0  = (tid >> 6) * 16;  // scatter d-range

  f32x4 acc[2][2];
#pragma unroll
  for (int i = 0; i < 2; i++)
#pragma unroll
    for (int j = 0; j < 2; j++) acc[i][j] = (f32x4){0.f, 0.f, 0.f, 0.f};

  for (int dc = 0; dc < DD; dc += 64) {
    // ---- A: Wk[dc+d][j0+j] -> Ab[j][d] ----
    {
      const float* s0 = Wk + (long)(dc + lrow) * DD + j0 + lc;
      float4 v0 = *(const float4*)(s0 + 0);
      float4 v1 = *(const float4*)(s0 + 4);
      float4 v2 = *(const float4*)(s0 + 8);
      float4 v3 = *(const float4*)(s0 + 12);
      *(float4*)&scr[lrow][lc + 0]  = v0;
      *(float4*)&scr[lrow][lc + 4]  = v1;
      *(float4*)&scr[lrow][lc + 8]  = v2;
      *(float4*)&scr[lrow][lc + 12] = v3;
    }
    __syncthreads();
#pragma unroll
    for (int g = 0; g < 4; g++) {
      ushort4 o;
      o.x = f2bf(scr[sd0 + g * 4 + 0][sj]);
      o.y = f2bf(scr[sd0 + g * 4 + 1][sj]);
      o.z = f2bf(scr[sd0 + g * 4 + 2][sj]);
      o.w = f2bf(scr[sd0 + g * 4 + 3][sj]);
      *(ushort4*)&Ab[sj * 72 + sd0 + g * 4] = o;
    }
    __syncthreads();
    // ---- B: Wq[dc+d][i0+i] -> Bb[i][d] ----
    {
      const float* s0 = Wq + (long)(dc + lrow) * DD + i0 + lc;
      float4 v0 = *(const float4*)(s0 + 0);
      float4 v1 = *(const float4*)(s0 + 4);
      float4 v2 = *(const float4*)(s0 + 8);
      float4 v3 = *(const float4*)(s0 + 12);
      *(float4*)&scr[lrow][lc + 0]  = v0;
      *(float4*)&scr[lrow][lc + 4]  = v1;
      *(float4*)&scr[lrow][lc + 8]  = v2;
      *(float4*)&scr[lrow][lc + 12] = v3;
    }
    __syncthreads();
#pragma unroll
    for (int g = 0; g < 4; g++) {
      ushort4 o;
      o.x = f2bf(scr[sd0 + g * 4 + 0][sj]);
      o.y = f2bf(scr[sd0 + g * 4 + 1][sj]);
      o.z = f2bf(scr[sd0 + g * 4 + 2][sj]);
      o.w = f2bf(scr[sd0 + g * 4 + 3][sj]);
      *(ushort4*)&Bb[sj * 72 + sd0 + g * 4] = o;
    }
    __syncthreads();
    // ---- 8 MFMA (2 k-steps x 2x2 fragments) ----
#pragma unroll
    for (int s = 0; s < 2; s++) {
      bf16x8 af[2], bf_[2];
#pragma unroll
      for (int i = 0; i < 2; i++)
        af[i] = *(const bf16x8*)&Ab[(wm + i * 16 + lm) * 72 + s * 32 +
                                    quad * 8];
#pragma unroll
      for (int j = 0; j < 2; j++)
        bf_[j] = *(const bf16x8*)&Bb[(wn + j * 16 + lm) * 72 + s * 32 +
                                     quad * 8];
#pragma unroll
      for (int i = 0; i < 2; i++)
#pragma unroll
        for (int j = 0; j < 2; j++)
          acc[i][j] = __builtin_amdgcn_mfma_f32_16x16x32_bf16(
              af[i], bf_[j], acc[i][j], 0, 0, 0);
    }
    __syncthreads();
  }
  const int baseRow = wm + quad * 4;
  const int baseCol = wn + lm;
#pragma unroll
  for (int i = 0; i < 2; i++)
#pragma unroll
    for (int r = 0; r < 4; r++)
#pragma unroll
      for (int j = 0; j < 2; j++)
        W2R[(long)(j0 + baseRow + i * 16 + r) * DD + i0 + baseCol + j * 16] =
            __float2bfloat16(acc[i][j][r]);
}

// ---------------------------------------------------------------------------
// k1 pack2 (4672 blocks): 4608 x/e pack jobs (one 32x32 tile each, R5's
// XCD-affine mapping: x-job b = j&7 so VT_b/xb_b land in XCD b's L2) +
// 64 W2R tiles computed directly from fp32 Wq/Wk. No WqT/WkT buffers.
// ---------------------------------------------------------------------------
__global__ __launch_bounds__(256, 4) void pack2_k(
    const float* __restrict__ x, const float* __restrict__ e,
    const float* __restrict__ Wq, const float* __restrict__ Wk, bf16* xb,
    bf16* VT, bf16* eb, bf16* ET, bf16* W2R) {
  __shared__ __align__(16) char smem[35072];
  const int j = blockIdx.x;
  if (j >= 4608) {
    const int i = j - 4608;  // 0..63
    w2r_tile(Wk, Wq, W2R, (i >> 3) * 64, (i & 7) * 64, smem);
    return;
  }
  float (*tile)[33] = reinterpret_cast<float (*)[33]>(smem);
  const int tid  = threadIdx.x;
  const int lrow = tid >> 3;        // 0..31
  const int lc4  = (tid & 7) * 4;   // float4 col
  const float* src; int ld;
  bf16 *dS, *dT; int ldS, ldT;
  if (j < 4096) {
    int b = j & 7;                  // XCD-affine
    int slot = j >> 3;
    int r = slot >> 3, c = slot & 7;
    src = x + ((long)b * NN + r * 32) * DIM_X + c * 32; ld = DIM_X;
    dS = xb + ((long)b * NN + r * 32) * DIM_X + c * 32; ldS = DIM_X;
    dT = VT + ((long)b * DIM_X + c * 32) * NN + r * 32; ldT = NN;
  } else {
    int i = j - 4096, r = i >> 3, c = i & 7;
    src = e + ((long)r * 32) * DIM_E + c * 32; ld = DIM_E;
    dS = eb + ((long)r * 32) * DIM_E + c * 32; ldS = DIM_E;
    dT = ET + ((long)c * 32) * NN + r * 32; ldT = NN;
  }
  float4 v = *(const float4*)(src + (long)lrow * ld + lc4);
  {
    ushort4 o;
    o.x = f2bf(v.x); o.y = f2bf(v.y); o.z = f2bf(v.z); o.w = f2bf(v.w);
    *(ushort4*)((unsigned short*)dS + (long)lrow * ldS + lc4) = o;
  }
  tile[lrow][lc4 + 0] = v.x; tile[lrow][lc4 + 1] = v.y;
  tile[lrow][lc4 + 2] = v.z; tile[lrow][lc4 + 3] = v.w;
  __syncthreads();
  {
    ushort4 o;
    o.x = f2bf(tile[lc4 + 0][lrow]);
    o.y = f2bf(tile[lc4 + 1][lrow]);
    o.z = f2bf(tile[lc4 + 2][lrow]);
    o.w = f2bf(tile[lc4 + 3][lrow]);
    *(ushort4*)((unsigned short*)dT + (long)lrow * ldT + lc4) = o;
  }
}

// ---------------------------------------------------------------------------
// k2 mid (1408 blocks, 48KB -> 3/CU): three independent job families, all
// depending only on k1:
//   blocks [0,256):     M_b = x_b^T @ [x_b | e]  (64x64 tiles, K=2048 full,
//                       b = bx&7 XCD-affine; M_b[t,j] over DD cols)
//   blocks [256,1280):  Px_b = xb_b @ W2R[:, :256]^T  (128x64, K=256)
//   blocks [1280,1408): E2 = eb @ W2R[:, 256:]^T (batch-shared, 128x64)
// M blocks dispatched first (longest) for makespan.
// ---------------------------------------------------------------------------
__global__ __launch_bounds__(256, 3) void mid_k(
    const bf16* VT, const bf16* ET, const bf16* xb, const bf16* eb,
    const bf16* W2R, bf16* M, bf16* Px, bf16* E2) {
  __shared__ __align__(16) char smem[49152];
  const int bx = blockIdx.x;
  if (bx < 256) {
    const int b  = bx & 7;
    const int idx = bx >> 3;            // 0..31
    const int mt = idx & 3;             // 4 x 64 = 256 rows (t)
    const int nt = idx >> 2;            // 8 x 64 = 512 cols (j)
    const bf16* A = VT + (long)b * DIM_X * NN + (long)mt * 64 * NN;
    const bf16* B = (nt < 4) ? VT + (long)b * DIM_X * NN + (long)nt * 64 * NN
                             : ET + (long)(nt - 4) * 64 * NN;
    gemm_tile<64, 64, 64, true, 0, 0>(
        A, nullptr, B, nullptr,
        M + (long)b * DIM_X * DD + (long)mt * 64 * DD + nt * 64, NN, NN, NN,
        DD, 1.0f, smem);
  } else if (bx < 1280) {
    const int i  = bx - 256;
    const int b  = i & 7;
    const int idx = i >> 3;             // 0..127
    const int nt = idx & 15;            // 16 x 128 = 2048 rows (n)
    const int ct = idx >> 4;            // 8 x 64 = 512 cols (j)
    gemm_tile<128, 64, 64, true, 0, 0>(
        xb + (long)b * NN * DIM_X + (long)nt * 128 * DIM_X, nullptr,
        W2R + (long)ct * 64 * DD, nullptr,
        Px + (long)b * NN * DD + (long)nt * 128 * DD + ct * 64, DIM_X, DIM_X,
        DD, DD, 1.0f, smem);
  } else {
    const int i  = bx - 1280;
    const int nt = i & 15;
    const int ct = i >> 4;
    gemm_tile<128, 64, 64, true, 0, 0>(
        eb + (long)nt * 128 * DIM_E, nullptr,
        W2R + DIM_X + (long)ct * 64 * DD, nullptr,
        E2 + (long)nt * 128 * DD + ct * 64, DIM_E, DIM_E, DD, DD, 1.0f,
        smem);
  }
}

// ---------------------------------------------------------------------------
// k3 out (256 blocks, 128x128 tiles, 64KB dbuf, 1/CU): K-concat GEMM
//   out_b = SCALE * [Px_b | E2] @ [M_b | M_b]^T   (K=1024)
// = SCALE * (Px_b + E2) @ M_b^T = SCALE * X_e,b W2 X_e,b^T x_b  == reference.
// ASPLIT=512 (A1=E2 batch-shared), BSPLIT=512 with B1=B0 (proven repeat
// trick). b = bx&7: Px_b, M_b XCD-L2-local.
// ---------------------------------------------------------------------------
__global__ __launch_bounds__(256, 2) void out_k(const bf16* Px,
                                                const bf16* E2, const bf16* M,
                                                float* out) {
  __shared__ __align__(16) char smem[65536];
  const int bx = blockIdx.x;
  const int b  = bx & 7;
  const int idx = bx >> 3;              // 0..31
  const int m  = idx & 15;              // 16 x 128 = 2048 rows (n)
  const int n  = idx >> 4;              // 2 x 128 = 256 cols (t)
  const bf16* Mb = M + (long)b * DIM_X * DD + (long)n * 128 * DD;
  gemm_tile<128, 128, 64, false, 512, 512>(
      Px + (long)b * NN * DD + (long)m * 128 * DD, E2 + (long)m * 128 * DD,
      Mb, Mb,
      out + (long)b * NN * DIM_X + (long)m * 128 * DIM_X + n * 128, 1024, DD,
      DD, DIM_X, SCALE, smem);
}

// ---------------------------------------------------------------------------

extern "C" void kernel_launch(void* const* d_in, const int* in_sizes, int n_in,
                              void* d_out, int out_size, void* d_ws,
                              size_t ws_size, hipStream_t stream) {
  const float* x  = (const float*)d_in[0];  // (8, 2048, 256)
  const float* e  = (const float*)d_in[1];  // (2048, 256)
  const float* Wq = (const float*)d_in[2];  // (512, 512)
  const float* Wk = (const float*)d_in[3];  // (512, 512)
  float* out = (float*)d_out;               // (8, 2048, 256)

  char* ws = (char*)d_ws;
  size_t off = 0;
  auto alloc = [&](size_t bytes) {
    void* p = ws + off;
    off += (bytes + 255) & ~(size_t)255;
    return p;
  };

  bf16* xb  = (bf16*)alloc((size_t)NB * NN * DIM_X * 2);  // 8.4 MB
  bf16* VT  = (bf16*)alloc((size_t)NB * DIM_X * NN * 2);  // 8.4 MB
  bf16* eb  = (bf16*)alloc((size_t)NN * DIM_E * 2);       // 1 MB
  bf16* ET  = (bf16*)alloc((size_t)DIM_E * NN * 2);       // 1 MB
  bf16* W2R = (bf16*)alloc((size_t)DD * DD * 2);          // 0.5 MB
  bf16* M   = (bf16*)alloc((size_t)NB * DIM_X * DD * 2);  // 2 MB
  bf16* Px  = (bf16*)alloc((size_t)NB * NN * DD * 2);     // 16.8 MB
  bf16* E2  = (bf16*)alloc((size_t)NN * DD * 2);          // 2 MB

  pack2_k<<<4672, 256, 0, stream>>>(x, e, Wq, Wk, xb, VT, eb, ET, W2R);
  mid_k<<<1408, 256, 0, stream>>>(VT, ET, xb, eb, W2R, M, Px, E2);
  out_k<<<256, 256, 0, stream>>>(Px, E2, M, out);
}

// Round 9
// 104.604 us; speedup vs baseline: 1.6616x; 1.2554x over previous
//
#include <hip/hip_runtime.h>
#include <hip/hip_bf16.h>

// Problem constants
#define DIM_X 256
#define DIM_E 256
#define DD    512          // DIM_X + DIM_E
#define NB    8            // batch
#define NN    2048         // sequence
#define SCALE 0.044194173824159216f   // (DIM_X+DIM_E)^-0.5

typedef __attribute__((ext_vector_type(8))) __bf16 bf16x8;
typedef __attribute__((ext_vector_type(4))) float  f32x4;
using bf16 = __hip_bfloat16;

__device__ __forceinline__ unsigned short f2bf(float f) {
  union { __hip_bfloat16 h; unsigned short u; } c;
  c.h = __float2bfloat16(f);
  return c.u;
}

// async global->LDS 16B copy. LDS dest must be wave-uniform base + lane*16.
__device__ __forceinline__ void async_lds16(const void* g, void* l) {
  using u32_as3 = __attribute__((address_space(3))) unsigned int;
  using u32_as1 = const __attribute__((address_space(1))) unsigned int;
  __builtin_amdgcn_global_load_lds(
      reinterpret_cast<u32_as1*>(reinterpret_cast<unsigned long long>(g)),
      reinterpret_cast<u32_as3*>(static_cast<unsigned int>(
          reinterpret_cast<unsigned long long>(l))),
      16, 0, 0);
}

// ---------------------------------------------------------------------------
// pack: 5120 32x32-tile jobs, one per block (HBM-floor ~7 us):
//   jobs [0,4096):     x -> xb (straight bf16) + VT (transpose)
//   jobs [4096,4608):  e -> eb (straight) + ET (transpose)
//   jobs [4608,4864):  Wq -> WqT (transpose)
//   jobs [4864,5120):  Wk -> WkT (transpose)
// ---------------------------------------------------------------------------
__global__ __launch_bounds__(256, 4) void pack_k(
    const float* __restrict__ x, const float* __restrict__ e,
    const float* __restrict__ Wq, const float* __restrict__ Wk, bf16* xb,
    bf16* VT, bf16* eb, bf16* ET, bf16* WqT, bf16* WkT) {
  __shared__ float tile[32][33];
  const int tid  = threadIdx.x;
  const int lrow = tid >> 3;        // 0..31 (load row)
  const int lc4  = (tid & 7) * 4;   // float4 col
  const int j    = blockIdx.x;
  const float* src; int ld;
  bf16 *dS = nullptr, *dT; int ldS = 0, ldT;
  if (j < 4096) {
    int b = j >> 9, r = (j >> 3) & 63, c = j & 7;
    src = x + ((long)b * NN + r * 32) * DIM_X + c * 32; ld = DIM_X;
    dS = xb + ((long)b * NN + r * 32) * DIM_X + c * 32; ldS = DIM_X;
    dT = VT + ((long)b * DIM_X + c * 32) * NN + r * 32; ldT = NN;
  } else if (j < 4608) {
    int i = j - 4096, r = i >> 3, c = i & 7;
    src = e + ((long)r * 32) * DIM_E + c * 32; ld = DIM_E;
    dS = eb + ((long)r * 32) * DIM_E + c * 32; ldS = DIM_E;
    dT = ET + ((long)c * 32) * NN + r * 32; ldT = NN;
  } else if (j < 4864) {
    int i = j - 4608, r = i >> 4, c = i & 15;
    src = Wq + ((long)r * 32) * DD + c * 32; ld = DD;
    dT = WqT + ((long)c * 32) * DD + r * 32; ldT = DD;
  } else {
    int i = j - 4864, r = i >> 4, c = i & 15;
    src = Wk + ((long)r * 32) * DD + c * 32; ld = DD;
    dT = WkT + ((long)c * 32) * DD + r * 32; ldT = DD;
  }
  float4 v = *(const float4*)(src + (long)lrow * ld + lc4);
  if (dS) {
    ushort4 o;
    o.x = f2bf(v.x); o.y = f2bf(v.y); o.z = f2bf(v.z); o.w = f2bf(v.w);
    *(ushort4*)((unsigned short*)dS + (long)lrow * ldS + lc4) = o;
  }
  tile[lrow][lc4 + 0] = v.x; tile[lrow][lc4 + 1] = v.y;
  tile[lrow][lc4 + 2] = v.z; tile[lrow][lc4 + 3] = v.w;
  __syncthreads();
  {
    ushort4 o;
    o.x = f2bf(tile[lc4 + 0][lrow]);
    o.y = f2bf(tile[lc4 + 1][lrow]);
    o.z = f2bf(tile[lc4 + 2][lrow]);
    o.w = f2bf(tile[lc4 + 3][lrow]);
    *(ushort4*)((unsigned short*)dT + (long)lrow * ldT + lc4) = o;
  }
}

// ---------------------------------------------------------------------------
// One BMxBN tile of C = alpha * Acat @ Bcat^T (operands K-major bf16).
// 4 waves 2x2, wave tile (BM/2)x(BN/2), 16x16x32 MFMA, XOR-swizzled LDS,
// global_load_lds width-16 staging, double-buffered (stage t+1 issued before
// compute of t; the single end-of-step barrier's vmcnt(0) drains it after
// the prefetch latency hid under the MFMAs).
// ASPLIT>0: for k>=ASPLIT read A1 at k-ASPLIT (K-concatenation of A0|A1).
// BSPLIT>0: same for B0|B1 (B1==B0 gives a K-repeated B).
// smem must be 2*(BM+BN)*BKt*2 bytes.
// ---------------------------------------------------------------------------
template <int BM, int BN, int BKt, bool OUT_BF16, int ASPLIT, int BSPLIT>
__device__ void gemm_tile(const bf16* __restrict__ A0,
                          const bf16* __restrict__ A1,
                          const bf16* __restrict__ B0,
                          const bf16* __restrict__ B1, void* __restrict__ Cv,
                          int K, int lda, int ldb, int ldc, float alpha,
                          char* smem) {
  constexpr int CPT  = BKt / 8;      // 16B chunks per row
  constexpr int KS   = BKt / 32;     // MFMA k-steps per staged tile
  constexpr int WTM  = BM / 2, WTN = BN / 2;
  constexpr int IM   = WTM / 16, IN = WTN / 16;
  constexpr int CA   = BM * CPT, CB = BN * CPT;
  constexpr int BUFB = (BM + BN) * BKt * 2;  // bytes per LDS buffer

  const int tid  = threadIdx.x;
  const int lane = tid & 63;
  const int wave = tid >> 6;
  const int lm   = lane & 15;
  const int quad = lane >> 4;
  const int wm   = (wave >> 1) * WTM;
  const int wn   = (wave & 1) * WTN;

  auto stage = [&](int t, int buf) {
    const int k0 = t * BKt;
    const bf16* Ak = A0; int ka = k0;
    if (ASPLIT > 0 && k0 >= ASPLIT) { Ak = A1; ka = k0 - ASPLIT; }
    const bf16* Bk = B0; int kb = k0;
    if (BSPLIT > 0 && k0 >= BSPLIT) { Bk = B1; kb = k0 - BSPLIT; }
    bf16* sA = (bf16*)(smem + (size_t)buf * BUFB);
    bf16* sB = sA + BM * BKt;
#pragma unroll
    for (int c = tid; c < CA; c += 256) {
      int row = c / CPT;
      int cb  = (c % CPT) ^ (row % CPT);
      async_lds16(Ak + (long)row * lda + ka + cb * 8, sA + (size_t)c * 8);
    }
#pragma unroll
    for (int c = tid; c < CB; c += 256) {
      int row = c / CPT;
      int cb  = (c % CPT) ^ (row % CPT);
      async_lds16(Bk + (long)row * ldb + kb + cb * 8, sB + (size_t)c * 8);
    }
  };

  f32x4 acc[IM][IN];
#pragma unroll
  for (int i = 0; i < IM; i++)
#pragma unroll
    for (int j = 0; j < IN; j++) acc[i][j] = (f32x4){0.f, 0.f, 0.f, 0.f};

  const int nt = K / BKt;
  stage(0, 0);
  __syncthreads();  // drains vmcnt(0): tile 0 resident
  int cur = 0;
  for (int t = 0; t < nt; ++t) {
    if (t + 1 < nt) stage(t + 1, cur ^ 1);  // prefetch overlaps compute below
    const bf16* sA = (const bf16*)(smem + (size_t)cur * BUFB);
    const bf16* sB = sA + BM * BKt;
    bf16x8 af[KS][IM], bfr[KS][IN];
#pragma unroll
    for (int s = 0; s < KS; s++) {
#pragma unroll
      for (int i = 0; i < IM; i++) {
        int r = wm + i * 16 + lm;
        af[s][i] = *(const bf16x8*)&sA[r * BKt +
                                       (((s * 4 + quad) ^ (r % CPT)) * 8)];
      }
#pragma unroll
      for (int j = 0; j < IN; j++) {
        int r = wn + j * 16 + lm;
        bfr[s][j] = *(const bf16x8*)&sB[r * BKt +
                                        (((s * 4 + quad) ^ (r % CPT)) * 8)];
      }
    }
#pragma unroll
    for (int s = 0; s < KS; s++)
#pragma unroll
      for (int i = 0; i < IM; i++)
#pragma unroll
        for (int j = 0; j < IN; j++)
          acc[i][j] = __builtin_amdgcn_mfma_f32_16x16x32_bf16(
              af[s][i], bfr[s][j], acc[i][j], 0, 0, 0);
    __syncthreads();  // readers done with buf cur; prefetch into cur^1 drained
    cur ^= 1;
  }

  // C/D layout (16x16): col = lane&15, row = (lane>>4)*4 + reg  [m89-verified]
  const int baseRow = wm + quad * 4;
  const int baseCol = wn + lm;
  if (OUT_BF16) {
    bf16* Cb = (bf16*)Cv;
#pragma unroll
    for (int i = 0; i < IM; i++)
#pragma unroll
      for (int r = 0; r < 4; r++) {
        int row = baseRow + i * 16 + r;
#pragma unroll
        for (int j = 0; j < IN; j++)
          Cb[(long)row * ldc + baseCol + j * 16] =
              __float2bfloat16(acc[i][j][r] * alpha);
      }
  } else {
    float* Cf = (float*)Cv;
#pragma unroll
    for (int i = 0; i < IM; i++)
#pragma unroll
      for (int r = 0; r < 4; r++) {
        int row = baseRow + i * 16 + r;
#pragma unroll
        for (int j = 0; j < IN; j++)
          Cf[(long)row * ldc + baseCol + j * 16] = acc[i][j][r] * alpha;
      }
  }
}

// ---------------------------------------------------------------------------
// phase1 (320 blocks, 48KB LDS -> up to 3/CU so the 64 W2T blocks co-schedule
// with M blocks instead of serializing):
//   blocks [0,256):   M half-K partials, 128x64 tiles (16 MFMA / 12 ds_read
//                     per wave-step), 256 jobs (b, mt in 2 x 128rows,
//                     nt in 8 x 64cols, kh in 2), K=1024 each, reduced in
//                     phase2 via K-concat. b = bx&7 keeps VT_b XCD-affine.
//   blocks [256,320): W2T = WqT @ WkT^T (64x64, K=512)
// ---------------------------------------------------------------------------
__global__ __launch_bounds__(256, 2) void phase1_k(
    const bf16* VT, const bf16* ET, const bf16* WqT, const bf16* WkT,
    bf16* M1, bf16* M2, bf16* W2T) {
  __shared__ __align__(16) char smem[49152];
  const int bx = blockIdx.x;
  if (bx < 256) {
    const int b   = bx & 7;
    const int idx = bx >> 3;              // 0..31
    const int kh  = idx & 1;              // K half
    const int mt  = (idx >> 1) & 1;       // row tile (2 x 128 = 256)
    const int nt  = idx >> 2;             // col tile (8 x 64 = 512)
    const bf16* A = VT + (long)b * DIM_X * NN + (long)mt * 128 * NN +
                    kh * 1024;
    const bf16* B = (nt < 4)
        ? VT + (long)b * DIM_X * NN + (long)nt * 64 * NN + kh * 1024
        : ET + (long)(nt - 4) * 64 * NN + kh * 1024;
    bf16* C = (kh ? M2 : M1) + (long)b * DIM_X * DD + (long)mt * 128 * DD +
              nt * 64;
    gemm_tile<128, 64, 64, true, 0, 0>(A, nullptr, B, nullptr, C, 1024, NN,
                                       NN, DD, 1.0f, smem);
  } else {
    const int i = bx - 256;
    int r2 = i >> 3, c2 = i & 7;
    gemm_tile<64, 64, 64, true, 0, 0>(
        WqT + (long)r2 * 64 * DD, nullptr, WkT + (long)c2 * 64 * DD, nullptr,
        W2T + (long)r2 * 64 * DD + c2 * 64, DD, DD, DD, DD, 1.0f, smem);
  }
}

// ---------------------------------------------------------------------------
// phase2 (512 blocks): R = SCALE * (M1+M2) @ W2T^T as K-concat GEMM K=1024
// ([M1|M2] @ [W2T|W2T]^T, ASPLIT=BSPLIT=512; verified rounds 1-8).
// 32x64 tiles, BK=128 dbuf (48KB), 2/CU resident.
// ---------------------------------------------------------------------------
__global__ __launch_bounds__(256, 3) void phase2_k(const bf16* M1,
                                                   const bf16* M2,
                                                   const bf16* W2T, bf16* R) {
  __shared__ __align__(16) char smem[49152];
  const int bx = blockIdx.x;
  const int b = bx & 7, r = (bx >> 3) & 7, c = bx >> 6;
  const bf16* a0 = M1 + (long)b * DIM_X * DD + (long)r * 32 * DD;
  const bf16* a1 = M2 + (long)b * DIM_X * DD + (long)r * 32 * DD;
  const bf16* w  = W2T + (long)c * 64 * DD;
  gemm_tile<32, 64, 128, true, 512, 512>(
      a0, a1, w, w, R + (long)b * DIM_X * DD + (long)r * 32 * DD + c * 64,
      1024, DD, DD, DD, SCALE, smem);
}

// ---------------------------------------------------------------------------
// phase3 (256 blocks): out = [xb|eb] @ R^T, 128x128 tiles (m97 per-wave
// shape: 64x64 wave tile, 32 MFMA / 16 ds_read per step), BK=64 dbuf = 64KB
// LDS, fp32 out, 1 block/CU, all 256 CUs busy. XCD-affine b = bx&7.
// ---------------------------------------------------------------------------
__global__ __launch_bounds__(256, 2) void phase3_k(const bf16* xb,
                                                   const bf16* eb,
                                                   const bf16* R, float* out) {
  __shared__ __align__(16) char smem[65536];
  const int bx = blockIdx.x;
  const int b = bx & 7, m = (bx >> 3) & 15, n = (bx >> 7) & 1;
  gemm_tile<128, 128, 64, false, 256, 0>(
      xb + (long)b * NN * DIM_X + (long)m * 128 * DIM_X,
      eb + (long)m * 128 * DIM_E,
      R + (long)b * DIM_X * DD + (long)n * 128 * DD, nullptr,
      out + (long)b * NN * DIM_X + (long)m * 128 * DIM_X + n * 128, DD,
      DIM_X, DD, DIM_X, 1.0f, smem);
}

// ---------------------------------------------------------------------------

extern "C" void kernel_launch(void* const* d_in, const int* in_sizes, int n_in,
                              void* d_out, int out_size, void* d_ws,
                              size_t ws_size, hipStream_t stream) {
  const float* x  = (const float*)d_in[0];  // (8, 2048, 256)
  const float* e  = (const float*)d_in[1];  // (2048, 256)
  const float* Wq = (const float*)d_in[2];  // (512, 512)
  const float* Wk = (const float*)d_in[3];  // (512, 512)
  float* out = (float*)d_out;               // (8, 2048, 256)

  char* ws = (char*)d_ws;
  size_t off = 0;
  auto alloc = [&](size_t bytes) {
    void* p = ws + off;
    off += (bytes + 255) & ~(size_t)255;
    return p;
  };

  bf16* xb  = (bf16*)alloc((size_t)NB * NN * DIM_X * 2);  // 8.4 MB
  bf16* VT  = (bf16*)alloc((size_t)NB * DIM_X * NN * 2);  // 8.4 MB
  bf16* eb  = (bf16*)alloc((size_t)NN * DIM_E * 2);       // 1 MB
  bf16* ET  = (bf16*)alloc((size_t)DIM_E * NN * 2);       // 1 MB
  bf16* WqT = (bf16*)alloc((size_t)DD * DD * 2);          // 0.5 MB
  bf16* WkT = (bf16*)alloc((size_t)DD * DD * 2);          // 0.5 MB
  bf16* W2T = (bf16*)alloc((size_t)DD * DD * 2);          // 0.5 MB
  bf16* M1  = (bf16*)alloc((size_t)NB * DIM_X * DD * 2);  // 2 MB
  bf16* M2  = (bf16*)alloc((size_t)NB * DIM_X * DD * 2);  // 2 MB
  bf16* R   = (bf16*)alloc((size_t)NB * DIM_X * DD * 2);  // 2 MB

  pack_k<<<5120, 256, 0, stream>>>(x, e, Wq, Wk, xb, VT, eb, ET, WqT, WkT);
  phase1_k<<<320, 256, 0, stream>>>(VT, ET, WqT, WkT, M1, M2, W2T);
  phase2_k<<<512, 256, 0, stream>>>(M1, M2, W2T, R);
  phase3_k<<<256, 256, 0, stream>>>(xb, eb, R, out);
}